// Round 2
// baseline (3799.800 us; speedup 1.0000x reference)
//
#include <hip/hip_runtime.h>

// LSTMTagger: B=32 T=512 V=32000 E=512 H=1024 (4H=4096) O=128
// bf16 MFMA w/ fp32 accumulate for gates.
//
// R2 restructure: shortest-possible serial chain per timestep.
//  front: e-MFMA -> poll(256 flags) -> h-stage -> barrier -> h-MFMA
//  back:  in-wave pointwise (shuffle gather, no LDS/no barrier) -> publish
//         (per-wave stores + vmcnt(0) + per-wave flag) -> project(t-1) ->
//         e-stage(t+1) into eA[(t+1)&1] (tokens LDS-resident) -> barrier
// 2 barriers/step (was 3), no gbuf, no wave-0 serialization, no token RT.
//
// ws layout (bytes) -- total 221184:
//   [0, 131072)        hbuf:  ushort[4 groups][2 bufs][8192]
//   [131072, 139264)   flags: uint[4 groups][256] used (region 8 KiB)
//   [139264, 204800)   vrows: ushort[32][1024]
//   [204800, 221184)   vlog:  float[32][128]

typedef short s8v __attribute__((ext_vector_type(8)));
typedef float f4v __attribute__((ext_vector_type(4)));
typedef unsigned int u4v __attribute__((ext_vector_type(4)));

#define WS_CNT_OFF   131072
#define WS_VROWS_OFF 139264
#define WS_VLOG_OFF  204800

__device__ __forceinline__ float b2f(unsigned short u) {
    union { unsigned int i; float f; } x; x.i = ((unsigned int)u) << 16; return x.f;
}
__device__ __forceinline__ unsigned short f2b(float f) {
    union { float f; unsigned int i; } x; x.f = f;
    unsigned int r = (x.i + 0x7fffu + ((x.i >> 16) & 1u)) >> 16;
    return (unsigned short)r;
}
__device__ __forceinline__ float blo(unsigned int u) {
    union { unsigned int i; float f; } x; x.i = u << 16; return x.f;
}
__device__ __forceinline__ float bhi(unsigned int u) {
    union { unsigned int i; float f; } x; x.i = u & 0xffff0000u; return x.f;
}

__global__ void init_kernel(unsigned int* ws) {
    int i = blockIdx.x * 256 + threadIdx.x;
    if (i < 34816) ws[i] = 0u;   // zero hbuf (131072B) + flags (8192B)
}

// Distributed output projection: WG computes cols {2w,2w+1} of
// logits[b0..b0+7, tproj, :] from hA (LDS, ko-stride 17 units).
__device__ __forceinline__ void project_cols(
    const short* hA, const float* __restrict__ Wr0, const float* __restrict__ Wr1,
    float* __restrict__ dout, int b0, int tproj, int w, int tid)
{
    const int pair = tid >> 4, p = tid & 15;
    const int b = pair >> 1, oc = pair & 1;
    const float* wr = oc ? Wr1 : Wr0;
    float acc = 0.f;
#pragma unroll
    for (int j = 0; j < 8; ++j) {
        int ko = j * 16 + p;
        u4v d = *(const u4v*)&hA[(ko * 17 + b) * 8];
        const float* wk = wr + ko * 8;
        f4v w0 = *(const f4v*)wk, w1 = *(const f4v*)(wk + 4);
        unsigned int d0 = d[0], d1 = d[1], d2 = d[2], d3 = d[3];
        acc += blo(d0) * w0[0] + bhi(d0) * w0[1] + blo(d1) * w0[2] + bhi(d1) * w0[3]
             + blo(d2) * w1[0] + bhi(d2) * w1[1] + blo(d3) * w1[2] + bhi(d3) * w1[3];
    }
#pragma unroll
    for (int off = 1; off < 16; off <<= 1) acc += __shfl_xor(acc, off);
    if (p == 0)
        dout[((size_t)(b0 + b) * 512 + tproj) * 128 + 2 * w + oc] = acc;
}

// ---------------------------------------------------------------------------
// Persistent LSTM scan. 256 WGs = 4 groups x 64 WGs. Group g: batches [8g,8g+8).
// WG w: hidden [16w,16w+16); wave v: gate-cols n = (c>>2)*1024 + 16w + 4v + (c&3).
// C-fragment (q=lane>>4, c=lane&15, reg r): batch = 4q+r, col = c.
// => wave v holds all 4 gates of hidden j = 16w+4v+jo at lanes c = gate*4+jo.
// ---------------------------------------------------------------------------
__global__ __launch_bounds__(256, 1) void scan_kernel(
    const int* __restrict__ tokens,
    const int* __restrict__ vidx,
    const float* __restrict__ emb,
    const float* __restrict__ W_ih,
    const float* __restrict__ W_hh,
    const float* __restrict__ b_ih,
    const float* __restrict__ b_hh,
    const float* __restrict__ W_lin,
    unsigned short* __restrict__ hbuf,
    unsigned int* __restrict__ flags_all,
    unsigned short* __restrict__ vrows,
    float* __restrict__ dout)
{
    __shared__ short hA[128 * 17 * 8];       // 34816 B (K=1024)
    __shared__ short eA[2][64 * 17 * 8];     // 2 x 17408 B (K=512, dbuf)
    __shared__ int   tokL[512 * 8];          // 16384 B, [t][b]

    const int tid  = threadIdx.x;
    const int g    = blockIdx.x >> 6;
    const int w    = blockIdx.x & 63;
    const int b0   = g * 8;
    const int lane = tid & 63;
    const int v    = tid >> 6;
    const int q    = lane >> 4;
    const int c    = lane & 15;

    const float* Wr0 = W_lin + (size_t)(2 * w) * 2048 + 1024;   // Wo rows
    const float* Wr1 = W_lin + (size_t)(2 * w + 1) * 2048 + 1024;

    // --- preload B fragments, fp32 -> bf16 (VGPR-resident all 512 steps) ---
    const int n = ((c >> 2) * 1024) + 16 * w + 4 * v + (c & 3);
    s8v Bh[32], Be[16];
    {
        const float* rh = W_hh + (size_t)n * 1024;
#pragma unroll
        for (int ks = 0; ks < 32; ++ks) {
            const float* s = rh + ks * 32 + q * 8;
            f4v lo = *(const f4v*)s, hi = *(const f4v*)(s + 4);
            s8v f;
#pragma unroll
            for (int j = 0; j < 4; ++j) { f[j] = (short)f2b(lo[j]); f[j + 4] = (short)f2b(hi[j]); }
            Bh[ks] = f;
        }
        const float* re = W_ih + (size_t)n * 512;
#pragma unroll
        for (int ks = 0; ks < 16; ++ks) {
            const float* s = re + ks * 32 + q * 8;
            f4v lo = *(const f4v*)s, hi = *(const f4v*)(s + 4);
            s8v f;
#pragma unroll
            for (int j = 0; j < 4; ++j) { f[j] = (short)f2b(lo[j]); f[j + 4] = (short)f2b(hi[j]); }
            Be[ks] = f;
        }
    }

    // tokens -> LDS ([t][b] layout)
    for (int i = tid; i < 4096; i += 256)
        tokL[(i & 511) * 8 + (i >> 9)] = tokens[(b0 + (i >> 9)) * 512 + (i & 511)];

    // zero MFMA pad rows 8..15 (written once)
    const s8v zv = {0,0,0,0,0,0,0,0};
    for (int i = tid; i < 1024; i += 256) { int ko = i >> 3, r = 8 + (i & 7);
        *(s8v*)&hA[(ko * 17 + r) * 8] = zv; }
    for (int i = tid; i < 512; i += 256) { int ko = i >> 3, r = 8 + (i & 7);
        *(s8v*)&eA[0][(ko * 17 + r) * 8] = zv;
        *(s8v*)&eA[1][(ko * 17 + r) * 8] = zv; }
    __syncthreads();

    // stage e(0) into eA[0] (reads tokL)
    for (int i = tid; i < 512; i += 256) {
        int ko = i >> 3, b = i & 7;
        int tok = tokL[b];
        const float* s = emb + (size_t)tok * 512 + ko * 8;
        f4v lo = *(const f4v*)s, hi = *(const f4v*)(s + 4);
        s8v f;
#pragma unroll
        for (int j = 0; j < 4; ++j) { f[j] = (short)f2b(lo[j]); f[j + 4] = (short)f2b(hi[j]); }
        *(s8v*)&eA[0][(ko * 17 + b) * 8] = f;
    }

    // per-lane pointwise constants
    const int jloc = 16 * w + 4 * v + (lane & 3);       // this lane's hidden idx
    const float bI = b_ih[jloc]        + b_hh[jloc];
    const float bF = b_ih[1024 + jloc] + b_hh[1024 + jloc];
    const float bG = b_ih[2048 + jloc] + b_hh[2048 + jloc];
    const float bO = b_ih[3072 + jloc] + b_hh[3072 + jloc];
    const int  shbase = (lane & 48) | (lane & 3);
    const bool stAct  = ((lane & 12) == 0) && (lane < 32) && !(lane & 1);
    const int  phid   = 8 * w + 2 * v + ((lane >> 1) & 1);
    const int  Db     = (phid >> 2) * 32 + (phid & 3) + (lane >> 4) * 16; // +r*4
    int tv0 = -1, tv1 = -1, tv2 = -1, tv3 = -1;
    if (stAct) {
        int bb = b0 + 4 * (lane >> 4);
        tv0 = vidx[bb]; tv1 = vidx[bb + 1]; tv2 = vidx[bb + 2]; tv3 = vidx[bb + 3];
    }
    const int vrb = (b0 + 4 * (lane >> 4)) * 1024 + jloc;  // +r*1024

    float cst[4] = {0.f, 0.f, 0.f, 0.f};
    unsigned short* hb     = hbuf + g * 2 * 8192;
    unsigned int*   hb32   = (unsigned int*)hb;
    unsigned int*   gflags = flags_all + g * 256;   // per-(WG,wave) flags
    int rp = 0;
    __syncthreads();

    for (int t = 0; t < 512; ++t) {
        // ---- e-part MFMA (K=512) from eA[t&1] ----
        f4v ae = {0.f, 0.f, 0.f, 0.f};
        const short* eAc = eA[t & 1];
#pragma unroll
        for (int ks = 0; ks < 16; ++ks) {
            s8v a = *(const s8v*)&eAc[((ks * 4 + q) * 17 + c) * 8];
            ae = __builtin_amdgcn_mfma_f32_16x16x32_bf16(a, Be[ks], ae, 0, 0, 0);
        }

        // ---- wait for h(t-1): 256 per-wave flags, 4 loads/lane ----
        if (t > 0) {
            const unsigned tt = (unsigned)t;
            for (;;) {
                unsigned f0 = __hip_atomic_load(&gflags[lane],       __ATOMIC_RELAXED, __HIP_MEMORY_SCOPE_AGENT);
                unsigned f1 = __hip_atomic_load(&gflags[64 + lane],  __ATOMIC_RELAXED, __HIP_MEMORY_SCOPE_AGENT);
                unsigned f2 = __hip_atomic_load(&gflags[128 + lane], __ATOMIC_RELAXED, __HIP_MEMORY_SCOPE_AGENT);
                unsigned f3 = __hip_atomic_load(&gflags[192 + lane], __ATOMIC_RELAXED, __HIP_MEMORY_SCOPE_AGENT);
                unsigned m01 = f0 < f1 ? f0 : f1;
                unsigned m23 = f2 < f3 ? f2 : f3;
                unsigned m = m01 < m23 ? m01 : m23;
                if (__all(m >= tt)) break;
            }
            asm volatile("" ::: "memory");   // no hoisting of h loads above poll
        }

        // ---- stage h(t-1): qword LLC-coherent loads -> LDS ----
        {
            const unsigned long long* src =
                (const unsigned long long*)(hb + rp * 8192);
#pragma unroll
            for (int it = 0; it < 8; ++it) {
                int j = it * 256 + tid;
                unsigned long long d = __hip_atomic_load(src + j, __ATOMIC_RELAXED,
                                                         __HIP_MEMORY_SCOPE_AGENT);
                int ko = j >> 4, b = (j >> 1) & 7, posq = (j & 1) << 2;
                *(unsigned long long*)&hA[(ko * 17 + b) * 8 + posq] = d;
            }
        }
        __syncthreads();   // MID: hA staged

        // ---- h-part MFMA (K=1024), 2 accumulator chains ----
        f4v ah0 = {0.f, 0.f, 0.f, 0.f}, ah1 = {0.f, 0.f, 0.f, 0.f};
#pragma unroll
        for (int ks = 0; ks < 16; ++ks) {
            s8v a0 = *(const s8v*)&hA[((2 * ks) * 4 + q) * 17 * 8 + c * 8];
            s8v a1 = *(const s8v*)&hA[((2 * ks + 1) * 4 + q) * 17 * 8 + c * 8];
            ah0 = __builtin_amdgcn_mfma_f32_16x16x32_bf16(a0, Bh[2 * ks], ah0, 0, 0, 0);
            ah1 = __builtin_amdgcn_mfma_f32_16x16x32_bf16(a1, Bh[2 * ks + 1], ah1, 0, 0, 0);
        }

        // ---- in-wave pointwise: shuffle-gather 4 gates, 4 cells/lane ----
        int hui[4];
#pragma unroll
        for (int r = 0; r < 4; ++r) {
            float s = ae[r] + ah0[r] + ah1[r];
            float xi = __shfl(s, shbase);
            float xf = __shfl(s, shbase + 4);
            float xg = __shfl(s, shbase + 8);
            float xo = __shfl(s, shbase + 12);
            float ig = 1.f / (1.f + __expf(-(xi + bI)));
            float fg = 1.f / (1.f + __expf(-(xf + bF)));
            float gg = 1.f - 2.f / (1.f + __expf(2.f * (xg + bG)));
            float og = 1.f / (1.f + __expf(-(xo + bO)));
            cst[r] = fg * cst[r] + ig * gg;
            float h = og * (1.f - 2.f / (1.f + __expf(2.f * cst[r])));
            hui[r] = (int)f2b(h);
        }
        // pack pairs (even jo lane takes partner's h as hi16) and publish
#pragma unroll
        for (int r = 0; r < 4; ++r) {
            int ph = __shfl_xor(hui[r], 1);
            if (stAct) {
                unsigned pack = (unsigned)hui[r] | (((unsigned)ph) << 16);
                __hip_atomic_store(&hb32[(rp ^ 1) * 4096 + Db + r * 4], pack,
                                   __ATOMIC_RELAXED, __HIP_MEMORY_SCOPE_AGENT);
                int tvr = (r == 0) ? tv0 : (r == 1) ? tv1 : (r == 2) ? tv2 : tv3;
                if (t == tvr)
                    *(unsigned int*)&vrows[vrb + r * 1024] = pack;
            }
        }
        // wave-local release: drain own stores to LLC, then per-wave flag
        asm volatile("s_waitcnt vmcnt(0)" ::: "memory");
        if (lane == 0)
            __hip_atomic_store(&gflags[w * 4 + v], (unsigned)(t + 1),
                               __ATOMIC_RELAXED, __HIP_MEMORY_SCOPE_AGENT);

        // ---- shadow work after publish: project h(t-1), stage e(t+2...) ----
        if (t >= 1)
            project_cols(hA, Wr0, Wr1, dout, b0, t - 1, w, tid);

        if (t < 511) {
            int tn = t + 1;
            short* eAn = eA[tn & 1];
            for (int i = tid; i < 512; i += 256) {
                int ko = i >> 3, b = i & 7;
                int tok = tokL[tn * 8 + b];
                const float* s2 = emb + (size_t)tok * 512 + ko * 8;
                f4v lo = *(const f4v*)s2, hi = *(const f4v*)(s2 + 4);
                s8v f;
#pragma unroll
                for (int j2 = 0; j2 < 4; ++j2) { f[j2] = (short)f2b(lo[j2]); f[j2 + 4] = (short)f2b(hi[j2]); }
                *(s8v*)&eAn[(ko * 17 + b) * 8] = f;
            }
        }
        __syncthreads();   // END: eA(t+1) staged, hA reads done
        rp ^= 1;
    }

    // ---- tail: fetch & project h(511) ----
    for (;;) {
        unsigned f0 = __hip_atomic_load(&gflags[lane],       __ATOMIC_RELAXED, __HIP_MEMORY_SCOPE_AGENT);
        unsigned f1 = __hip_atomic_load(&gflags[64 + lane],  __ATOMIC_RELAXED, __HIP_MEMORY_SCOPE_AGENT);
        unsigned f2 = __hip_atomic_load(&gflags[128 + lane], __ATOMIC_RELAXED, __HIP_MEMORY_SCOPE_AGENT);
        unsigned f3 = __hip_atomic_load(&gflags[192 + lane], __ATOMIC_RELAXED, __HIP_MEMORY_SCOPE_AGENT);
        unsigned m01 = f0 < f1 ? f0 : f1;
        unsigned m23 = f2 < f3 ? f2 : f3;
        unsigned m = m01 < m23 ? m01 : m23;
        if (__all(m >= 512u)) break;
    }
    asm volatile("" ::: "memory");
    {
        const unsigned long long* src = (const unsigned long long*)(hb + rp * 8192);
#pragma unroll
        for (int it = 0; it < 8; ++it) {
            int j = it * 256 + tid;
            unsigned long long d = __hip_atomic_load(src + j, __ATOMIC_RELAXED,
                                                     __HIP_MEMORY_SCOPE_AGENT);
            int ko = j >> 4, b = (j >> 1) & 7, posq = (j & 1) << 2;
            *(unsigned long long*)&hA[(ko * 17 + b) * 8 + posq] = d;
        }
    }
    __syncthreads();
    project_cols(hA, Wr0, Wr1, dout, b0, 511, w, tid);
}

// ---------------------------------------------------------------------------
// vlog[b][o] = vrows[b,:] . Wv[o,:] + b_lin[o]
// ---------------------------------------------------------------------------
__global__ void verb_kernel(const unsigned short* __restrict__ vrows,
                            const float* __restrict__ W_lin,
                            const float* __restrict__ b_lin,
                            float* __restrict__ vlog)
{
    __shared__ float vrow[1024];
    int b = blockIdx.x, tid = threadIdx.x;
    for (int i = tid; i < 1024; i += 256) vrow[i] = b2f(vrows[b * 1024 + i]);
    __syncthreads();
    if (tid < 128) {
        float acc = 0.f;
        const float* wr = W_lin + (size_t)tid * 2048;
        for (int h = 0; h < 1024; ++h) acc += vrow[h] * wr[h];
        vlog[b * 128 + tid] = acc + b_lin[tid];
    }
}

// ---------------------------------------------------------------------------
// In-place: dout[b,t,:] = log_softmax(dout[b,t,:] + vlog[b,:])
// ---------------------------------------------------------------------------
__global__ void softmax_kernel(float* __restrict__ dout,
                               const float* __restrict__ vlog)
{
    int tid = threadIdx.x;
    int grow = blockIdx.x * 32 + (tid >> 3);
    int part = tid & 7;
    int b = grow >> 9;
    float* pp = dout + (size_t)grow * 128 + part * 16;
    const float* vb = vlog + b * 128 + part * 16;
    float L[16];
#pragma unroll
    for (int i = 0; i < 16; ++i) L[i] = pp[i] + vb[i];
    float m = L[0];
#pragma unroll
    for (int i = 1; i < 16; ++i) m = fmaxf(m, L[i]);
    for (int off = 1; off < 8; off <<= 1) m = fmaxf(m, __shfl_xor(m, off));
    float s = 0.f;
#pragma unroll
    for (int i = 0; i < 16; ++i) s += expf(L[i] - m);
    for (int off = 1; off < 8; off <<= 1) s += __shfl_xor(s, off);
    float lz = m + logf(s);
#pragma unroll
    for (int i = 0; i < 16; ++i) pp[i] = L[i] - lz;
}

extern "C" void kernel_launch(void* const* d_in, const int* in_sizes, int n_in,
                              void* d_out, int out_size, void* d_ws, size_t ws_size,
                              hipStream_t stream) {
    const int*   tokens = (const int*)d_in[0];
    const int*   vidx   = (const int*)d_in[1];
    const float* emb    = (const float*)d_in[2];
    const float* W_ih   = (const float*)d_in[3];
    const float* W_hh   = (const float*)d_in[4];
    const float* b_ih   = (const float*)d_in[5];
    const float* b_hh   = (const float*)d_in[6];
    const float* W_lin  = (const float*)d_in[7];
    const float* b_lin  = (const float*)d_in[8];
    float* dout = (float*)d_out;

    char* ws = (char*)d_ws;
    unsigned short* hbuf  = (unsigned short*)ws;
    unsigned int*   flags = (unsigned int*)(ws + WS_CNT_OFF);
    unsigned short* vrows = (unsigned short*)(ws + WS_VROWS_OFF);
    float*          vlog  = (float*)(ws + WS_VLOG_OFF);

    init_kernel<<<136, 256, 0, stream>>>((unsigned int*)ws);
    scan_kernel<<<256, 256, 0, stream>>>(tokens, vidx, emb, W_ih, W_hh, b_ih, b_hh,
                                         W_lin, hbuf, flags, vrows, dout);
    verb_kernel<<<32, 256, 0, stream>>>(vrows, W_lin, b_lin, vlog);
    softmax_kernel<<<512, 256, 0, stream>>>(dout, vlog);
}

// Round 3
// 3320.746 us; speedup vs baseline: 1.1443x; 1.1443x over previous
//
#include <hip/hip_runtime.h>

// LSTMTagger: B=32 T=512 V=32000 E=512 H=1024 (4H=4096) O=128
// bf16 MFMA w/ fp32 accumulate for gates.
//
// R3: decongest the all-to-all. Producer wave v of WG w owns exactly the
// hbuf qwords j with (j&1)==(v&1), ((j>>4)&1)==(v>>1). Consumer wave v
// stages only class-v qwords and polls only the 64 class-v flags (one
// per-WG-wave flag, spread 32B apart). Backoff poll (2 tight iters then
// s_sleep). Publish as paired qword stores (no partial-line amplification).
// h-loads issued in 4+4 batches interleaved with e-MFMA halves.
//
// ws layout (bytes) -- total 221184:
//   [0, 131072)        hbuf:  ushort[4 groups][2 bufs][8192]
//   [131072, 139264)   flags: uint[4 groups][256 flags x 8 spread]
//   [139264, 204800)   vrows: ushort[32][1024]
//   [204800, 221184)   vlog:  float[32][128]

typedef short s8v __attribute__((ext_vector_type(8)));
typedef float f4v __attribute__((ext_vector_type(4)));
typedef unsigned int u4v __attribute__((ext_vector_type(4)));

#define WS_CNT_OFF   131072
#define WS_VROWS_OFF 139264
#define WS_VLOG_OFF  204800

__device__ __forceinline__ float b2f(unsigned short u) {
    union { unsigned int i; float f; } x; x.i = ((unsigned int)u) << 16; return x.f;
}
__device__ __forceinline__ unsigned short f2b(float f) {
    union { float f; unsigned int i; } x; x.f = f;
    unsigned int r = (x.i + 0x7fffu + ((x.i >> 16) & 1u)) >> 16;
    return (unsigned short)r;
}
__device__ __forceinline__ float blo(unsigned int u) {
    union { unsigned int i; float f; } x; x.i = u << 16; return x.f;
}
__device__ __forceinline__ float bhi(unsigned int u) {
    union { unsigned int i; float f; } x; x.i = u & 0xffff0000u; return x.f;
}

__global__ void init_kernel(unsigned int* ws) {
    int i = blockIdx.x * 256 + threadIdx.x;
    if (i < 34816) ws[i] = 0u;   // zero hbuf (131072B) + flags (8192B)
}

// Distributed output projection: WG computes cols {2w,2w+1} of
// logits[b0..b0+7, tproj, :] from hA (LDS, ko-stride 17 units).
__device__ __forceinline__ void project_cols(
    const short* hA, const float* __restrict__ Wr0, const float* __restrict__ Wr1,
    float* __restrict__ dout, int b0, int tproj, int w, int tid)
{
    const int pair = tid >> 4, p = tid & 15;
    const int b = pair >> 1, oc = pair & 1;
    const float* wr = oc ? Wr1 : Wr0;
    float acc = 0.f;
#pragma unroll
    for (int j = 0; j < 8; ++j) {
        int ko = j * 16 + p;
        u4v d = *(const u4v*)&hA[(ko * 17 + b) * 8];
        const float* wk = wr + ko * 8;
        f4v w0 = *(const f4v*)wk, w1 = *(const f4v*)(wk + 4);
        unsigned int d0 = d[0], d1 = d[1], d2 = d[2], d3 = d[3];
        acc += blo(d0) * w0[0] + bhi(d0) * w0[1] + blo(d1) * w0[2] + bhi(d1) * w0[3]
             + blo(d2) * w1[0] + bhi(d2) * w1[1] + blo(d3) * w1[2] + bhi(d3) * w1[3];
    }
#pragma unroll
    for (int off = 1; off < 16; off <<= 1) acc += __shfl_xor(acc, off);
    if (p == 0)
        dout[((size_t)(b0 + b) * 512 + tproj) * 128 + 2 * w + oc] = acc;
}

// ---------------------------------------------------------------------------
// Persistent LSTM scan. 256 WGs = 4 groups x 64 WGs. Group g: batches [8g,8g+8).
// WG w: hidden [16w,16w+16); wave v: gate-cols n = (c>>2)*1024 + 16w + 4v + (c&3).
// C-fragment (q=lane>>4, c=lane&15, reg r): batch = 4q+r, col = c.
// hbuf dword D(P=hidden-pair, b=batch) = (P>>2)*32 + b*4 + (P&3).
// Producer wave v owns P = 8w+2v+{0,1} -> qword class (j&1, (j>>4)&1) = (v&1, v>>1).
// ---------------------------------------------------------------------------
__global__ __launch_bounds__(256, 1) void scan_kernel(
    const int* __restrict__ tokens,
    const int* __restrict__ vidx,
    const float* __restrict__ emb,
    const float* __restrict__ W_ih,
    const float* __restrict__ W_hh,
    const float* __restrict__ b_ih,
    const float* __restrict__ b_hh,
    const float* __restrict__ W_lin,
    unsigned short* __restrict__ hbuf,
    unsigned int* __restrict__ flags_all,
    unsigned short* __restrict__ vrows,
    float* __restrict__ dout)
{
    __shared__ short hA[128 * 17 * 8];       // 34816 B (K=1024)
    __shared__ short eA[2][64 * 17 * 8];     // 2 x 17408 B (K=512, dbuf)
    __shared__ int   tokL[512 * 8];          // 16384 B, [t][b]

    const int tid  = threadIdx.x;
    const int g    = blockIdx.x >> 6;
    const int w    = blockIdx.x & 63;
    const int b0   = g * 8;
    const int lane = tid & 63;
    const int v    = tid >> 6;
    const int q    = lane >> 4;
    const int c    = lane & 15;

    const float* Wr0 = W_lin + (size_t)(2 * w) * 2048 + 1024;   // Wo rows
    const float* Wr1 = W_lin + (size_t)(2 * w + 1) * 2048 + 1024;

    // --- preload B fragments, fp32 -> bf16 (VGPR-resident all 512 steps) ---
    const int n = ((c >> 2) * 1024) + 16 * w + 4 * v + (c & 3);
    s8v Bh[32], Be[16];
    {
        const float* rh = W_hh + (size_t)n * 1024;
#pragma unroll
        for (int ks = 0; ks < 32; ++ks) {
            const float* s = rh + ks * 32 + q * 8;
            f4v lo = *(const f4v*)s, hi = *(const f4v*)(s + 4);
            s8v f;
#pragma unroll
            for (int j = 0; j < 4; ++j) { f[j] = (short)f2b(lo[j]); f[j + 4] = (short)f2b(hi[j]); }
            Bh[ks] = f;
        }
        const float* re = W_ih + (size_t)n * 512;
#pragma unroll
        for (int ks = 0; ks < 16; ++ks) {
            const float* s = re + ks * 32 + q * 8;
            f4v lo = *(const f4v*)s, hi = *(const f4v*)(s + 4);
            s8v f;
#pragma unroll
            for (int j = 0; j < 4; ++j) { f[j] = (short)f2b(lo[j]); f[j + 4] = (short)f2b(hi[j]); }
            Be[ks] = f;
        }
    }

    // tokens -> LDS ([t][b] layout)
    for (int i = tid; i < 4096; i += 256)
        tokL[(i & 511) * 8 + (i >> 9)] = tokens[(b0 + (i >> 9)) * 512 + (i & 511)];

    // zero MFMA pad rows 8..15 (written once)
    const s8v zv = {0,0,0,0,0,0,0,0};
    for (int i = tid; i < 1024; i += 256) { int ko = i >> 3, r = 8 + (i & 7);
        *(s8v*)&hA[(ko * 17 + r) * 8] = zv; }
    for (int i = tid; i < 512; i += 256) { int ko = i >> 3, r = 8 + (i & 7);
        *(s8v*)&eA[0][(ko * 17 + r) * 8] = zv;
        *(s8v*)&eA[1][(ko * 17 + r) * 8] = zv; }
    __syncthreads();

    // stage e(0) into eA[0] (reads tokL)
    for (int i = tid; i < 512; i += 256) {
        int ko = i >> 3, b = i & 7;
        int tok = tokL[b];
        const float* s = emb + (size_t)tok * 512 + ko * 8;
        f4v lo = *(const f4v*)s, hi = *(const f4v*)(s + 4);
        s8v f;
#pragma unroll
        for (int j = 0; j < 4; ++j) { f[j] = (short)f2b(lo[j]); f[j + 4] = (short)f2b(hi[j]); }
        *(s8v*)&eA[0][(ko * 17 + b) * 8] = f;
    }

    // per-lane pointwise constants
    const int jloc = 16 * w + 4 * v + (lane & 3);       // this lane's hidden idx
    const float bI = b_ih[jloc]        + b_hh[jloc];
    const float bF = b_ih[1024 + jloc] + b_hh[1024 + jloc];
    const float bG = b_ih[2048 + jloc] + b_hh[2048 + jloc];
    const float bO = b_ih[3072 + jloc] + b_hh[3072 + jloc];
    const int  shbase = (lane & 48) | (lane & 3);
    const bool stActV = ((lane & 13) == 0) && (lane < 32);   // lanes {0,2,16,18}: vrows
    const bool stActQ = ((lane & 15) == 0) && (lane < 32);   // lanes {0,16}: qword publish
    // qword base: D(bit=0) = (2w+(v>>1))*32 + 2*(v&1) + 16q  (even)
    const int  Dq = ((2 * w + (v >> 1)) * 32 + 2 * (v & 1) + 16 * q) >> 1;
    int tv0 = -1, tv1 = -1, tv2 = -1, tv3 = -1;
    if (stActV) {
        int bb = b0 + 4 * (lane >> 4);
        tv0 = vidx[bb]; tv1 = vidx[bb + 1]; tv2 = vidx[bb + 2]; tv3 = vidx[bb + 3];
    }
    const int vrb = (b0 + 4 * (lane >> 4)) * 1024 + jloc;  // +r*1024

    float cst[4] = {0.f, 0.f, 0.f, 0.f};
    unsigned short*     hb     = hbuf + g * 2 * 8192;
    unsigned long long* hb64   = (unsigned long long*)hb;
    unsigned int*       gflags = flags_all + g * 2048;   // 256 flags x 8-dword spread
    const int fidx = (lane * 4 + v) * 8;                 // flag of (WG=lane, wave=v)
    const int myflag = (w * 4 + v) * 8;
    int rp = 0;
    __syncthreads();

    for (int t = 0; t < 512; ++t) {
        // ---- wait for h(t-1): class-v flags only, backoff poll ----
        if (t > 0) {
            const unsigned tt = (unsigned)t;
            for (int spin = 0; ; ++spin) {
                unsigned f = __hip_atomic_load(&gflags[fidx], __ATOMIC_RELAXED,
                                               __HIP_MEMORY_SCOPE_AGENT);
                if (__all(f >= tt)) break;
                if (spin >= 2) __builtin_amdgcn_s_sleep(2);
            }
            asm volatile("" ::: "memory");   // no hoisting of h loads above poll
        }

        // ---- stage h(t-1) class-v qwords, 4+4 interleaved with e-MFMA ----
        const unsigned long long* src =
            (const unsigned long long*)(hb + rp * 8192);
        const short* eAc = eA[t & 1];
        f4v ae = {0.f, 0.f, 0.f, 0.f};
        {
            unsigned long long dbuf[4]; int jarr[4];
#pragma unroll
            for (int it = 0; it < 4; ++it) {
                int i = ((it + w) & 7) * 64 + lane;
                int j = (((((i >> 3) << 1) | (v >> 1)) << 4) | ((i & 7) << 1) | (v & 1));
                jarr[it] = j;
                dbuf[it] = __hip_atomic_load(src + j, __ATOMIC_RELAXED,
                                             __HIP_MEMORY_SCOPE_AGENT);
            }
#pragma unroll
            for (int ks = 0; ks < 8; ++ks) {
                s8v a = *(const s8v*)&eAc[((ks * 4 + q) * 17 + c) * 8];
                ae = __builtin_amdgcn_mfma_f32_16x16x32_bf16(a, Be[ks], ae, 0, 0, 0);
            }
#pragma unroll
            for (int it = 0; it < 4; ++it) {
                int j = jarr[it];
                int ko = j >> 4, b = (j >> 1) & 7, posq = (j & 1) << 2;
                *(unsigned long long*)&hA[(ko * 17 + b) * 8 + posq] = dbuf[it];
            }
#pragma unroll
            for (int it = 4; it < 8; ++it) {
                int i = ((it + w) & 7) * 64 + lane;
                int j = (((((i >> 3) << 1) | (v >> 1)) << 4) | ((i & 7) << 1) | (v & 1));
                jarr[it - 4] = j;
                dbuf[it - 4] = __hip_atomic_load(src + j, __ATOMIC_RELAXED,
                                                 __HIP_MEMORY_SCOPE_AGENT);
            }
#pragma unroll
            for (int ks = 8; ks < 16; ++ks) {
                s8v a = *(const s8v*)&eAc[((ks * 4 + q) * 17 + c) * 8];
                ae = __builtin_amdgcn_mfma_f32_16x16x32_bf16(a, Be[ks], ae, 0, 0, 0);
            }
#pragma unroll
            for (int it = 0; it < 4; ++it) {
                int j = jarr[it];
                int ko = j >> 4, b = (j >> 1) & 7, posq = (j & 1) << 2;
                *(unsigned long long*)&hA[(ko * 17 + b) * 8 + posq] = dbuf[it];
            }
        }
        __syncthreads();   // MID: hA staged (all classes)

        // ---- h-part MFMA (K=1024), 2 accumulator chains ----
        f4v ah0 = {0.f, 0.f, 0.f, 0.f}, ah1 = {0.f, 0.f, 0.f, 0.f};
#pragma unroll
        for (int ks = 0; ks < 16; ++ks) {
            s8v a0 = *(const s8v*)&hA[((2 * ks) * 4 + q) * 17 * 8 + c * 8];
            s8v a1 = *(const s8v*)&hA[((2 * ks + 1) * 4 + q) * 17 * 8 + c * 8];
            ah0 = __builtin_amdgcn_mfma_f32_16x16x32_bf16(a0, Bh[2 * ks], ah0, 0, 0, 0);
            ah1 = __builtin_amdgcn_mfma_f32_16x16x32_bf16(a1, Bh[2 * ks + 1], ah1, 0, 0, 0);
        }

        // ---- in-wave pointwise: shuffle-gather 4 gates, 4 cells/lane ----
        int hui[4];
#pragma unroll
        for (int r = 0; r < 4; ++r) {
            float s = ae[r] + ah0[r] + ah1[r];
            float xi = __shfl(s, shbase);
            float xf = __shfl(s, shbase + 4);
            float xg = __shfl(s, shbase + 8);
            float xo = __shfl(s, shbase + 12);
            float ig = 1.f / (1.f + __expf(-(xi + bI)));
            float fg = 1.f / (1.f + __expf(-(xf + bF)));
            float gg = 1.f - 2.f / (1.f + __expf(2.f * (xg + bG)));
            float og = 1.f / (1.f + __expf(-(xo + bO)));
            cst[r] = fg * cst[r] + ig * gg;
            float h = og * (1.f - 2.f / (1.f + __expf(2.f * cst[r])));
            hui[r] = (int)f2b(h);
        }
        // pack pairs and publish as full qwords (lanes {0,16})
#pragma unroll
        for (int r = 0; r < 4; ++r) {
            int ph = __shfl_xor(hui[r], 1);
            unsigned pack = (unsigned)hui[r] | (((unsigned)ph) << 16);
            unsigned hi = (unsigned)__shfl_xor((int)pack, 2);
            if (stActQ) {
                unsigned long long pk = (unsigned long long)pack |
                                        (((unsigned long long)hi) << 32);
                __hip_atomic_store(&hb64[(rp ^ 1) * 1024 + Dq + r * 2], pk,
                                   __ATOMIC_RELAXED, __HIP_MEMORY_SCOPE_AGENT);
            }
            if (stActV) {
                int tvr = (r == 0) ? tv0 : (r == 1) ? tv1 : (r == 2) ? tv2 : tv3;
                if (t == tvr)
                    *(unsigned int*)&vrows[vrb + r * 1024] = pack;
            }
        }
        // wave-local release: drain own stores to LLC, then per-wave flag
        asm volatile("s_waitcnt vmcnt(0)" ::: "memory");
        if (lane == 0)
            __hip_atomic_store(&gflags[myflag], (unsigned)(t + 1),
                               __ATOMIC_RELAXED, __HIP_MEMORY_SCOPE_AGENT);

        // ---- shadow work after publish: project h(t-1), stage e(t+1) ----
        if (t >= 1)
            project_cols(hA, Wr0, Wr1, dout, b0, t - 1, w, tid);

        if (t < 511) {
            int tn = t + 1;
            short* eAn = eA[tn & 1];
            for (int i = tid; i < 512; i += 256) {
                int ko = i >> 3, b = i & 7;
                int tok = tokL[tn * 8 + b];
                const float* s2 = emb + (size_t)tok * 512 + ko * 8;
                f4v lo = *(const f4v*)s2, hi = *(const f4v*)(s2 + 4);
                s8v f;
#pragma unroll
                for (int j2 = 0; j2 < 4; ++j2) { f[j2] = (short)f2b(lo[j2]); f[j2 + 4] = (short)f2b(hi[j2]); }
                *(s8v*)&eAn[(ko * 17 + b) * 8] = f;
            }
        }
        __syncthreads();   // END: eA(t+1) staged, hA reads done
        rp ^= 1;
    }

    // ---- tail: fetch & project h(511) ----
    for (int spin = 0; ; ++spin) {
        unsigned f = __hip_atomic_load(&gflags[fidx], __ATOMIC_RELAXED,
                                       __HIP_MEMORY_SCOPE_AGENT);
        if (__all(f >= 512u)) break;
        if (spin >= 2) __builtin_amdgcn_s_sleep(2);
    }
    asm volatile("" ::: "memory");
    {
        const unsigned long long* src = (const unsigned long long*)(hb + rp * 8192);
#pragma unroll
        for (int it = 0; it < 8; ++it) {
            int i = ((it + w) & 7) * 64 + lane;
            int j = (((((i >> 3) << 1) | (v >> 1)) << 4) | ((i & 7) << 1) | (v & 1));
            unsigned long long d = __hip_atomic_load(src + j, __ATOMIC_RELAXED,
                                                     __HIP_MEMORY_SCOPE_AGENT);
            int ko = j >> 4, b = (j >> 1) & 7, posq = (j & 1) << 2;
            *(unsigned long long*)&hA[(ko * 17 + b) * 8 + posq] = d;
        }
    }
    __syncthreads();
    project_cols(hA, Wr0, Wr1, dout, b0, 511, w, tid);
}

// ---------------------------------------------------------------------------
// vlog[b][o] = vrows[b,:] . Wv[o,:] + b_lin[o]
// ---------------------------------------------------------------------------
__global__ void verb_kernel(const unsigned short* __restrict__ vrows,
                            const float* __restrict__ W_lin,
                            const float* __restrict__ b_lin,
                            float* __restrict__ vlog)
{
    __shared__ float vrow[1024];
    int b = blockIdx.x, tid = threadIdx.x;
    for (int i = tid; i < 1024; i += 256) vrow[i] = b2f(vrows[b * 1024 + i]);
    __syncthreads();
    if (tid < 128) {
        float acc = 0.f;
        const float* wr = W_lin + (size_t)tid * 2048;
        for (int h = 0; h < 1024; ++h) acc += vrow[h] * wr[h];
        vlog[b * 128 + tid] = acc + b_lin[tid];
    }
}

// ---------------------------------------------------------------------------
// In-place: dout[b,t,:] = log_softmax(dout[b,t,:] + vlog[b,:])
// ---------------------------------------------------------------------------
__global__ void softmax_kernel(float* __restrict__ dout,
                               const float* __restrict__ vlog)
{
    int tid = threadIdx.x;
    int grow = blockIdx.x * 32 + (tid >> 3);
    int part = tid & 7;
    int b = grow >> 9;
    float* pp = dout + (size_t)grow * 128 + part * 16;
    const float* vb = vlog + b * 128 + part * 16;
    float L[16];
#pragma unroll
    for (int i = 0; i < 16; ++i) L[i] = pp[i] + vb[i];
    float m = L[0];
#pragma unroll
    for (int i = 1; i < 16; ++i) m = fmaxf(m, L[i]);
    for (int off = 1; off < 8; off <<= 1) m = fmaxf(m, __shfl_xor(m, off));
    float s = 0.f;
#pragma unroll
    for (int i = 0; i < 16; ++i) s += expf(L[i] - m);
    for (int off = 1; off < 8; off <<= 1) s += __shfl_xor(s, off);
    float lz = m + logf(s);
#pragma unroll
    for (int i = 0; i < 16; ++i) pp[i] = L[i] - lz;
}

extern "C" void kernel_launch(void* const* d_in, const int* in_sizes, int n_in,
                              void* d_out, int out_size, void* d_ws, size_t ws_size,
                              hipStream_t stream) {
    const int*   tokens = (const int*)d_in[0];
    const int*   vidx   = (const int*)d_in[1];
    const float* emb    = (const float*)d_in[2];
    const float* W_ih   = (const float*)d_in[3];
    const float* W_hh   = (const float*)d_in[4];
    const float* b_ih   = (const float*)d_in[5];
    const float* b_hh   = (const float*)d_in[6];
    const float* W_lin  = (const float*)d_in[7];
    const float* b_lin  = (const float*)d_in[8];
    float* dout = (float*)d_out;

    char* ws = (char*)d_ws;
    unsigned short* hbuf  = (unsigned short*)ws;
    unsigned int*   flags = (unsigned int*)(ws + WS_CNT_OFF);
    unsigned short* vrows = (unsigned short*)(ws + WS_VROWS_OFF);
    float*          vlog  = (float*)(ws + WS_VLOG_OFF);

    init_kernel<<<136, 256, 0, stream>>>((unsigned int*)ws);
    scan_kernel<<<256, 256, 0, stream>>>(tokens, vidx, emb, W_ih, W_hh, b_ih, b_hh,
                                         W_lin, hbuf, flags, vrows, dout);
    verb_kernel<<<32, 256, 0, stream>>>(vrows, W_lin, b_lin, vlog);
    softmax_kernel<<<512, 256, 0, stream>>>(dout, vlog);
}

// Round 6
// 3297.327 us; speedup vs baseline: 1.1524x; 1.0071x over previous
//
#include <hip/hip_runtime.h>

// LSTMTagger: B=32 T=512 V=32000 E=512 H=1024 (4H=4096) O=128
// bf16 MFMA w/ fp32 accumulate for gates.
//
// R6: wait-free 2-transit protocol, ZERO numeric corruption.
//  - 3-buffer ring: h(t) -> buf[t%3]. At step t consumers poll buf[(t-1)%3],
//    producers publish buf[t%3], and (post-MID) zero their own qwords of
//    buf[(t+1)%3] (retiring h(t-2), provably fully-consumed).
//  - Published qwords encoded as (data ^ 0x7F807F807F807F80): encoded 0 would
//    require all four bf16 == +inf (impossible for h = sigmoid*tanh), so
//    "nonzero" == "current". Bit-exact h, no tag bits.
//  - Producer: fire-and-forget store. Consumer: 8 loads overlapped with
//    e-MFMA, accept-nonzero, retry stale. Zero->publish ordering via the
//    pre-publish s_waitcnt vmcnt(0).
//  - vrows/verb_kernel deleted: verb row is projected from hA (LDS) at step
//    tvb+1 straight into vlog (frees ws for the 3rd buffer).
//
// ws layout (bytes) -- total 212992 used:
//   [0, 196608)        hbuf: ushort[4 groups][3 bufs][8192]  (buf = 2048 qw)
//   [196608, 212992)   vlog: float[32][128]

typedef short s8v __attribute__((ext_vector_type(8)));
typedef float f4v __attribute__((ext_vector_type(4)));
typedef unsigned int u4v __attribute__((ext_vector_type(4)));

#define WS_VLOG_OFF 196608
#define ENC_MASK 0x7F807F807F807F80ULL

__device__ __forceinline__ float b2f(unsigned short u) {
    union { unsigned int i; float f; } x; x.i = ((unsigned int)u) << 16; return x.f;
}
__device__ __forceinline__ unsigned short f2b(float f) {
    union { float f; unsigned int i; } x; x.f = f;
    unsigned int r = (x.i + 0x7fffu + ((x.i >> 16) & 1u)) >> 16;
    return (unsigned short)r;
}
__device__ __forceinline__ float blo(unsigned int u) {
    union { unsigned int i; float f; } x; x.i = u << 16; return x.f;
}
__device__ __forceinline__ float bhi(unsigned int u) {
    union { unsigned int i; float f; } x; x.i = u & 0xffff0000u; return x.f;
}

// zero hbuf (196608B) + vlog (16384B) = 53248 dwords
__global__ void init_kernel(unsigned int* ws) {
    int i = blockIdx.x * 256 + threadIdx.x;
    if (i < 53248) ws[i] = 0u;
}

// Distributed output projection: WG computes cols {2w,2w+1} of
// logits[b0..b0+7, tproj, :] from hA (LDS, ko-stride 17 units).
__device__ __forceinline__ void project_cols(
    const short* hA, const float* __restrict__ Wr0, const float* __restrict__ Wr1,
    float* __restrict__ dout, int b0, int tproj, int w, int tid)
{
    const int pair = tid >> 4, p = tid & 15;
    const int b = pair >> 1, oc = pair & 1;
    const float* wr = oc ? Wr1 : Wr0;
    float acc = 0.f;
#pragma unroll
    for (int j = 0; j < 8; ++j) {
        int ko = j * 16 + p;
        u4v d = *(const u4v*)&hA[(ko * 17 + b) * 8];
        const float* wk = wr + ko * 8;
        f4v w0 = *(const f4v*)wk, w1 = *(const f4v*)(wk + 4);
        unsigned int d0 = d[0], d1 = d[1], d2 = d[2], d3 = d[3];
        acc += blo(d0) * w0[0] + bhi(d0) * w0[1] + blo(d1) * w0[2] + bhi(d1) * w0[3]
             + blo(d2) * w1[0] + bhi(d2) * w1[1] + blo(d3) * w1[2] + bhi(d3) * w1[3];
    }
#pragma unroll
    for (int off = 1; off < 16; off <<= 1) acc += __shfl_xor(acc, off);
    if (p == 0)
        dout[((size_t)(b0 + b) * 512 + tproj) * 128 + 2 * w + oc] = acc;
}

// Verb projection: if hA currently holds h(tprev) and tprev == vidx[batch bb],
// project that batch through Wv (W_lin cols [0,1024)) into vlog.
__device__ __forceinline__ void verb_cols(
    const short* hA, const float* __restrict__ W_lin, float* __restrict__ vlog,
    int b0, int w, int tid, const int* tvL, int tprev)
{
    const int pair = tid >> 4, p = tid & 15;
    const int bb = pair >> 1, oc = pair & 1;
    if (tvL[bb] != tprev) return;        // uniform over each 16-lane group
    const float* wr = W_lin + (size_t)(2 * w + oc) * 2048;   // Wv rows
    float acc = 0.f;
#pragma unroll
    for (int j = 0; j < 8; ++j) {
        int ko = j * 16 + p;
        u4v d = *(const u4v*)&hA[(ko * 17 + bb) * 8];
        const float* wk = wr + ko * 8;
        f4v w0 = *(const f4v*)wk, w1 = *(const f4v*)(wk + 4);
        acc += blo(d[0]) * w0[0] + bhi(d[0]) * w0[1] + blo(d[1]) * w0[2] + bhi(d[1]) * w0[3]
             + blo(d[2]) * w1[0] + bhi(d[2]) * w1[1] + blo(d[3]) * w1[2] + bhi(d[3]) * w1[3];
    }
#pragma unroll
    for (int off = 1; off < 16; off <<= 1) acc += __shfl_xor(acc, off);
    if (p == 0)
        vlog[(b0 + bb) * 128 + 2 * w + oc] = acc;
}

// ---------------------------------------------------------------------------
// Persistent LSTM scan. 256 WGs = 4 groups x 64 WGs. Group g: batches [8g,8g+8).
// WG w: hidden [16w,16w+16); wave v: gate-cols n = (c>>2)*1024 + 16w + 4v + (c&3).
// C-fragment (q=lane>>4, c=lane&15, reg r): batch = 4q+r, col = c.
// hbuf qword j <-> (b=(j>>1)&7, hid-oct ko=j>>4, half posq=(j&1)<<2);
// producer wave v of WG w owns j = (2w+(v>>1))*16 + b*2 + (v&1).
// ---------------------------------------------------------------------------
__global__ __launch_bounds__(256, 1) void scan_kernel(
    const int* __restrict__ tokens,
    const int* __restrict__ vidx,
    const float* __restrict__ emb,
    const float* __restrict__ W_ih,
    const float* __restrict__ W_hh,
    const float* __restrict__ b_ih,
    const float* __restrict__ b_hh,
    const float* __restrict__ W_lin,
    unsigned short* __restrict__ hbuf,
    float* __restrict__ vlog,
    float* __restrict__ dout)
{
    __shared__ short hA[128 * 17 * 8];       // 34816 B (K=1024)
    __shared__ short eA[2][64 * 17 * 8];     // 2 x 17408 B (K=512, dbuf)
    __shared__ int   tokL[512 * 8];          // 16384 B, [t][b]
    __shared__ int   tvL[8];

    const int tid  = threadIdx.x;
    const int g    = blockIdx.x >> 6;
    const int w    = blockIdx.x & 63;
    const int b0   = g * 8;
    const int lane = tid & 63;
    const int v    = tid >> 6;
    const int q    = lane >> 4;
    const int c    = lane & 15;

    const float* Wr0 = W_lin + (size_t)(2 * w) * 2048 + 1024;   // Wo rows
    const float* Wr1 = W_lin + (size_t)(2 * w + 1) * 2048 + 1024;

    // --- preload B fragments, fp32 -> bf16 (VGPR-resident all 512 steps) ---
    const int n = ((c >> 2) * 1024) + 16 * w + 4 * v + (c & 3);
    s8v Bh[32], Be[16];
    {
        const float* rh = W_hh + (size_t)n * 1024;
#pragma unroll
        for (int ks = 0; ks < 32; ++ks) {
            const float* s = rh + ks * 32 + q * 8;
            f4v lo = *(const f4v*)s, hi = *(const f4v*)(s + 4);
            s8v f;
#pragma unroll
            for (int j = 0; j < 4; ++j) { f[j] = (short)f2b(lo[j]); f[j + 4] = (short)f2b(hi[j]); }
            Bh[ks] = f;
        }
        const float* re = W_ih + (size_t)n * 512;
#pragma unroll
        for (int ks = 0; ks < 16; ++ks) {
            const float* s = re + ks * 32 + q * 8;
            f4v lo = *(const f4v*)s, hi = *(const f4v*)(s + 4);
            s8v f;
#pragma unroll
            for (int j = 0; j < 4; ++j) { f[j] = (short)f2b(lo[j]); f[j + 4] = (short)f2b(hi[j]); }
            Be[ks] = f;
        }
    }

    // tokens -> LDS ([t][b] layout); verb indices -> LDS
    for (int i = tid; i < 4096; i += 256)
        tokL[(i & 511) * 8 + (i >> 9)] = tokens[(b0 + (i >> 9)) * 512 + (i & 511)];
    if (tid < 8) tvL[tid] = vidx[b0 + tid];

    // zero ALL hA rows (0..7 data for t=0 h(-1)=0; 8..15 MFMA pad) + eA pads
    const s8v zv = {0,0,0,0,0,0,0,0};
    for (int i = tid; i < 2048; i += 256) { int ko = i >> 4, r = i & 15;
        *(s8v*)&hA[(ko * 17 + r) * 8] = zv; }
    for (int i = tid; i < 512; i += 256) { int ko = i >> 3, r = 8 + (i & 7);
        *(s8v*)&eA[0][(ko * 17 + r) * 8] = zv;
        *(s8v*)&eA[1][(ko * 17 + r) * 8] = zv; }
    __syncthreads();

    // stage e(0) into eA[0] (reads tokL)
    for (int i = tid; i < 512; i += 256) {
        int ko = i >> 3, b = i & 7;
        int tok = tokL[b];
        const float* s = emb + (size_t)tok * 512 + ko * 8;
        f4v lo = *(const f4v*)s, hi = *(const f4v*)(s + 4);
        s8v f;
#pragma unroll
        for (int j = 0; j < 4; ++j) { f[j] = (short)f2b(lo[j]); f[j + 4] = (short)f2b(hi[j]); }
        *(s8v*)&eA[0][(ko * 17 + b) * 8] = f;
    }

    // per-lane pointwise constants
    const int jloc = 16 * w + 4 * v + (lane & 3);       // this lane's hidden idx
    const float bI = b_ih[jloc]        + b_hh[jloc];
    const float bF = b_ih[1024 + jloc] + b_hh[1024 + jloc];
    const float bG = b_ih[2048 + jloc] + b_hh[2048 + jloc];
    const float bO = b_ih[3072 + jloc] + b_hh[3072 + jloc];
    const int  shbase = (lane & 48) | (lane & 3);
    const bool stActQ = ((lane & 15) == 0) && (lane < 32);   // lanes {0,16}
    const int  Dq = (2 * w + (v >> 1)) * 16 + (v & 1) + 8 * q;  // + r*2

    float cst[4] = {0.f, 0.f, 0.f, 0.f};
    unsigned long long* hb64 = (unsigned long long*)(hbuf + g * 3 * 8192);
    int rd = 2, wr = 0, zr = 1;   // at step t: rd=(t+2)%3, wr=t%3, zr=(t+1)%3
    __syncthreads();

    for (int t = 0; t < 512; ++t) {
        // ---- poll+stage h(t-1) from buf rd, overlapped with e-MFMA ----
        const unsigned long long* src = hb64 + rd * 2048;
        const short* eAc = eA[t & 1];
        f4v ae = {0.f, 0.f, 0.f, 0.f};
        if (t > 0) {
            unsigned long long d[8];
#pragma unroll
            for (int it = 0; it < 8; ++it) {
                int j = ((it + w) & 7) * 256 + tid;   // w-stagger de-convoys
                d[it] = __hip_atomic_load(src + j, __ATOMIC_RELAXED,
                                          __HIP_MEMORY_SCOPE_AGENT);
            }
            asm volatile("" ::: "memory");
#pragma unroll
            for (int ks = 0; ks < 16; ++ks) {
                s8v a = *(const s8v*)&eAc[((ks * 4 + q) * 17 + c) * 8];
                ae = __builtin_amdgcn_mfma_f32_16x16x32_bf16(a, Be[ks], ae, 0, 0, 0);
            }
            unsigned pend = 255u;
            while (pend) {
                unsigned np = 0;
#pragma unroll
                for (int it = 0; it < 8; ++it) {
                    if (pend & (1u << it)) {
                        if (d[it] != 0ULL) {
                            unsigned long long dd = d[it] ^ ENC_MASK;
                            int j = ((it + w) & 7) * 256 + tid;
                            int ko = j >> 4, b = (j >> 1) & 7, posq = (j & 1) << 2;
                            *(unsigned long long*)&hA[(ko * 17 + b) * 8 + posq] = dd;
                        } else {
                            np |= 1u << it;
                        }
                    }
                }
#pragma unroll
                for (int it = 0; it < 8; ++it) {
                    if (np & (1u << it)) {
                        int j = ((it + w) & 7) * 256 + tid;
                        d[it] = __hip_atomic_load(src + j, __ATOMIC_RELAXED,
                                                  __HIP_MEMORY_SCOPE_AGENT);
                    }
                }
                pend = np;
            }
        } else {
#pragma unroll
            for (int ks = 0; ks < 16; ++ks) {
                s8v a = *(const s8v*)&eAc[((ks * 4 + q) * 17 + c) * 8];
                ae = __builtin_amdgcn_mfma_f32_16x16x32_bf16(a, Be[ks], ae, 0, 0, 0);
            }
        }
        __syncthreads();   // MID: hA staged; all h(t-1) verified by this WG

        // ---- retire h(t-2): zero own qwords of buf zr (lands under MFMA) ----
        if (stActQ) {
#pragma unroll
            for (int r = 0; r < 4; ++r)
                __hip_atomic_store(&hb64[zr * 2048 + Dq + r * 2], 0ULL,
                                   __ATOMIC_RELAXED, __HIP_MEMORY_SCOPE_AGENT);
        }

        // ---- h-part MFMA (K=1024), 2 accumulator chains ----
        f4v ah0 = {0.f, 0.f, 0.f, 0.f}, ah1 = {0.f, 0.f, 0.f, 0.f};
#pragma unroll
        for (int ks = 0; ks < 16; ++ks) {
            s8v a0 = *(const s8v*)&hA[((2 * ks) * 4 + q) * 17 * 8 + c * 8];
            s8v a1 = *(const s8v*)&hA[((2 * ks + 1) * 4 + q) * 17 * 8 + c * 8];
            ah0 = __builtin_amdgcn_mfma_f32_16x16x32_bf16(a0, Bh[2 * ks], ah0, 0, 0, 0);
            ah1 = __builtin_amdgcn_mfma_f32_16x16x32_bf16(a1, Bh[2 * ks + 1], ah1, 0, 0, 0);
        }

        // ---- in-wave pointwise: shuffle-gather 4 gates, 4 cells/lane ----
        int hui[4];
#pragma unroll
        for (int r = 0; r < 4; ++r) {
            float s = ae[r] + ah0[r] + ah1[r];
            float xi = __shfl(s, shbase);
            float xf = __shfl(s, shbase + 4);
            float xg = __shfl(s, shbase + 8);
            float xo = __shfl(s, shbase + 12);
            float ig = 1.f / (1.f + __expf(-(xi + bI)));
            float fg = 1.f / (1.f + __expf(-(xf + bF)));
            float gg = 1.f - 2.f / (1.f + __expf(2.f * (xg + bG)));
            float og = 1.f / (1.f + __expf(-(xo + bO)));
            cst[r] = fg * cst[r] + ig * gg;
            float h = og * (1.f - 2.f / (1.f + __expf(2.f * cst[r])));
            hui[r] = (int)f2b(h);
        }
        // order: retire-zeros committed before publish becomes visible
        asm volatile("s_waitcnt vmcnt(0)" ::: "memory");
        // pack pairs, encode, publish (lanes {0,16}); fire-and-forget
#pragma unroll
        for (int r = 0; r < 4; ++r) {
            int phh = __shfl_xor(hui[r], 1);
            unsigned pack = (unsigned)hui[r] | (((unsigned)phh) << 16);
            unsigned hi = (unsigned)__shfl_xor((int)pack, 2);
            if (stActQ) {
                unsigned long long pk = ((unsigned long long)pack |
                                         (((unsigned long long)hi) << 32)) ^ ENC_MASK;
                __hip_atomic_store(&hb64[wr * 2048 + Dq + r * 2], pk,
                                   __ATOMIC_RELAXED, __HIP_MEMORY_SCOPE_AGENT);
            }
        }

        // ---- shadow work: project h(t-1) (dout + verb), stage e(t+1) ----
        if (t >= 1) {
            project_cols(hA, Wr0, Wr1, dout, b0, t - 1, w, tid);
            verb_cols(hA, W_lin, vlog, b0, w, tid, tvL, t - 1);
        }

        if (t < 511) {
            int tn = t + 1;
            short* eAn = eA[tn & 1];
            for (int i = tid; i < 512; i += 256) {
                int ko = i >> 3, b = i & 7;
                int tok = tokL[tn * 8 + b];
                const float* s2 = emb + (size_t)tok * 512 + ko * 8;
                f4v lo = *(const f4v*)s2, hi = *(const f4v*)(s2 + 4);
                s8v f;
#pragma unroll
                for (int j2 = 0; j2 < 4; ++j2) { f[j2] = (short)f2b(lo[j2]); f[j2 + 4] = (short)f2b(hi[j2]); }
                *(s8v*)&eAn[(ko * 17 + b) * 8] = f;
            }
        }
        __syncthreads();   // END: eA(t+1) staged, hA reads done
        int nrd = wr; wr = zr; zr = rd; rd = nrd;   // rotate ring
    }

    // ---- tail: poll+stage h(511) from buf rd, project it ----
    {
        const unsigned long long* src = hb64 + rd * 2048;
        unsigned long long d[8];
#pragma unroll
        for (int it = 0; it < 8; ++it) {
            int j = ((it + w) & 7) * 256 + tid;
            d[it] = __hip_atomic_load(src + j, __ATOMIC_RELAXED,
                                      __HIP_MEMORY_SCOPE_AGENT);
        }
        unsigned pend = 255u;
        while (pend) {
            unsigned np = 0;
#pragma unroll
            for (int it = 0; it < 8; ++it) {
                if (pend & (1u << it)) {
                    if (d[it] != 0ULL) {
                        unsigned long long dd = d[it] ^ ENC_MASK;
                        int j = ((it + w) & 7) * 256 + tid;
                        int ko = j >> 4, b = (j >> 1) & 7, posq = (j & 1) << 2;
                        *(unsigned long long*)&hA[(ko * 17 + b) * 8 + posq] = dd;
                    } else {
                        np |= 1u << it;
                    }
                }
            }
#pragma unroll
            for (int it = 0; it < 8; ++it) {
                if (np & (1u << it)) {
                    int j = ((it + w) & 7) * 256 + tid;
                    d[it] = __hip_atomic_load(src + j, __ATOMIC_RELAXED,
                                              __HIP_MEMORY_SCOPE_AGENT);
                }
            }
            pend = np;
        }
    }
    __syncthreads();
    project_cols(hA, Wr0, Wr1, dout, b0, 511, w, tid);
    verb_cols(hA, W_lin, vlog, b0, w, tid, tvL, 511);
}

// ---------------------------------------------------------------------------
// In-place: dout[b,t,:] = log_softmax(dout[b,t,:] + vlog[b,:] + b_lin)
// ---------------------------------------------------------------------------
__global__ void softmax_kernel(float* __restrict__ dout,
                               const float* __restrict__ vlog,
                               const float* __restrict__ b_lin)
{
    int tid = threadIdx.x;
    int grow = blockIdx.x * 32 + (tid >> 3);
    int part = tid & 7;
    int b = grow >> 9;
    float* pp = dout + (size_t)grow * 128 + part * 16;
    const float* vb = vlog + b * 128 + part * 16;
    const float* bl = b_lin + part * 16;
    float L[16];
#pragma unroll
    for (int i = 0; i < 16; ++i) L[i] = pp[i] + vb[i] + bl[i];
    float m = L[0];
#pragma unroll
    for (int i = 1; i < 16; ++i) m = fmaxf(m, L[i]);
    for (int off = 1; off < 8; off <<= 1) m = fmaxf(m, __shfl_xor(m, off));
    float s = 0.f;
#pragma unroll
    for (int i = 0; i < 16; ++i) s += expf(L[i] - m);
    for (int off = 1; off < 8; off <<= 1) s += __shfl_xor(s, off);
    float lz = m + logf(s);
#pragma unroll
    for (int i = 0; i < 16; ++i) pp[i] = L[i] - lz;
}

extern "C" void kernel_launch(void* const* d_in, const int* in_sizes, int n_in,
                              void* d_out, int out_size, void* d_ws, size_t ws_size,
                              hipStream_t stream) {
    const int*   tokens = (const int*)d_in[0];
    const int*   vidx   = (const int*)d_in[1];
    const float* emb    = (const float*)d_in[2];
    const float* W_ih   = (const float*)d_in[3];
    const float* W_hh   = (const float*)d_in[4];
    const float* b_ih   = (const float*)d_in[5];
    const float* b_hh   = (const float*)d_in[6];
    const float* W_lin  = (const float*)d_in[7];
    const float* b_lin  = (const float*)d_in[8];
    float* dout = (float*)d_out;

    char* ws = (char*)d_ws;
    unsigned short* hbuf = (unsigned short*)ws;
    float*          vlog = (float*)(ws + WS_VLOG_OFF);

    init_kernel<<<208, 256, 0, stream>>>((unsigned int*)ws);
    scan_kernel<<<256, 256, 0, stream>>>(tokens, vidx, emb, W_ih, W_hh, b_ih, b_hh,
                                         W_lin, hbuf, vlog, dout);
    softmax_kernel<<<512, 256, 0, stream>>>(dout, vlog, b_lin);
}